// Round 1
// baseline (989.567 us; speedup 1.0000x reference)
//
#include <hip/hip_runtime.h>
#include <math.h>

#define BB 64
#define SS 4096
#define DXX 512
#define QQ 128
#define DQQ 512
#define SPLITS 32
#define CHUNK (SS / SPLITS)            // 128 rows per block
#define NWAVES 4
#define ROWS_PER_WAVE (CHUNK / NWAVES) // 32
#define RB 4                           // rows per group
#define NGROUPS (ROWS_PER_WAVE / RB)   // 8 groups per wave

typedef float v4 __attribute__((ext_vector_type(4)));

// ---------------------------------------------------------------------------
// Kernel 1: first[b,:] = (sum_q p[q]*query[b,q,:]) @ W        [B, DX]
// ---------------------------------------------------------------------------
__global__ __launch_bounds__(512) void compute_first(
        const float* __restrict__ qm, const float* __restrict__ W,
        const float* __restrict__ p, float* __restrict__ first) {
    int b = blockIdx.x;
    int t = threadIdx.x;                    // 0..511
    __shared__ float sp[QQ];
    __shared__ float snq[DQQ];
    if (t < QQ) sp[t] = p[t];
    __syncthreads();

    const float* qb = qm + (size_t)b * QQ * DQQ + t;
    float acc = 0.f;
    #pragma unroll 8
    for (int q = 0; q < QQ; ++q) acc = fmaf(qb[(size_t)q * DQQ], sp[q], acc);
    snq[t] = acc;
    __syncthreads();

    float f = 0.f;
    #pragma unroll 8
    for (int dq = 0; dq < DQQ; ++dq) f = fmaf(snq[dq], W[(size_t)dq * DXX + t], f);
    first[b * DXX + t] = f;
}

// ---------------------------------------------------------------------------
// Kernel 2: flash-style single pass over x. One wave per s-row, RB=4 rows per
// group, register double-buffered so ~16 KB/wave of loads stay in flight while
// the butterfly+exp+accumulate tail runs. Branchless online softmax: exact
// same arithmetic as the branchy fast path (alpha == 1.0f on the common path),
// but no exec-mask divergence, so the scheduler can pipeline across groups.
// Grid: B*SPLITS = 2048 blocks x 256 threads.
// ---------------------------------------------------------------------------
__global__ __launch_bounds__(256, 4) void attn_partial(
        const float* __restrict__ x, const float* __restrict__ first,
        float* __restrict__ pm, float* __restrict__ pl,
        float* __restrict__ pacc) {
    const int blk  = blockIdx.x;
    const int b    = blk / SPLITS;
    const int sp   = blk % SPLITS;
    const int tid  = threadIdx.x;
    const int wave = tid >> 6;
    const int lane = tid & 63;

    const float* fb = first + b * DXX;
    const v4 f0 = *(const v4*)(fb + lane * 4);
    const v4 f1 = *(const v4*)(fb + 256 + lane * 4);

    float m = -1e30f, l = 0.f;
    v4 a0 = {0.f, 0.f, 0.f, 0.f};
    v4 a1 = {0.f, 0.f, 0.f, 0.f};

    // this wave's first row; its rows stride NWAVES within the chunk
    const float* xw = x + (size_t)b * SS * DXX
                        + (size_t)(sp * CHUNK + wave) * DXX + lane * 4;
    const size_t rstep = (size_t)NWAVES * DXX;   // floats between this wave's rows

    v4 pa0[RB], pa1[RB], pb0[RB], pb1[RB];

#define LOADG(buf0, buf1, g)                                                 \
    {                                                                        \
        _Pragma("unroll")                                                    \
        for (int r = 0; r < RB; ++r) {                                       \
            const float* xr = xw + (size_t)((g) * RB + r) * rstep;           \
            buf0[r] = *(const v4*)(xr);                                      \
            buf1[r] = *(const v4*)(xr + 256);                                \
        }                                                                    \
    }

#define PROCESS(buf0, buf1)                                                  \
    {                                                                        \
        float d[RB];                                                         \
        _Pragma("unroll")                                                    \
        for (int r = 0; r < RB; ++r) {                                       \
            v4 t4 = f0 * buf0[r] + f1 * buf1[r];                             \
            d[r] = (t4.x + t4.y) + (t4.z + t4.w);                            \
        }                                                                    \
        _Pragma("unroll")                                                    \
        for (int off = 32; off > 0; off >>= 1) {                             \
            _Pragma("unroll")                                                \
            for (int r = 0; r < RB; ++r) d[r] += __shfl_xor(d[r], off, 64);  \
        }                                                                    \
        _Pragma("unroll")                                                    \
        for (int r = 0; r < RB; ++r) {                                       \
            const float nm    = fmaxf(m, d[r]);                              \
            const float alpha = __expf(m - nm);      /* == 1.0f usually */   \
            const float w     = __expf(d[r] - nm);                           \
            m = nm;                                                          \
            l = fmaf(l, alpha, w);                                           \
            a0 = a0 * alpha + buf0[r] * w;                                   \
            a1 = a1 * alpha + buf1[r] * w;                                   \
        }                                                                    \
    }

    // prologue: preload group 0
    LOADG(pa0, pa1, 0);

    // steady state: always one full group (8 x dwordx4 / lane) in flight
    #pragma unroll
    for (int g = 0; g < NGROUPS - 2; g += 2) {
        LOADG(pb0, pb1, g + 1);
        PROCESS(pa0, pa1);
        LOADG(pa0, pa1, g + 2);
        PROCESS(pb0, pb1);
    }
    // epilogue: groups NGROUPS-2 and NGROUPS-1 (no out-of-bounds prefetch)
    LOADG(pb0, pb1, NGROUPS - 1);
    PROCESS(pa0, pa1);
    PROCESS(pb0, pb1);

#undef LOADG
#undef PROCESS

    // merge the 4 waves of this block in LDS
    __shared__ float sm[NWAVES];
    __shared__ float sl[NWAVES];
    __shared__ float sacc[NWAVES][DXX];     // 8 KiB
    if (lane == 0) { sm[wave] = m; sl[wave] = l; }
    float* sa = sacc[wave];
    *(v4*)(sa + lane * 4)       = a0;
    *(v4*)(sa + 256 + lane * 4) = a1;
    __syncthreads();

    const float M  = fmaxf(fmaxf(sm[0], sm[1]), fmaxf(sm[2], sm[3]));
    const float e0 = __expf(sm[0] - M), e1 = __expf(sm[1] - M);
    const float e2 = __expf(sm[2] - M), e3 = __expf(sm[3] - M);
    if (tid == 0) {
        pm[blk] = M;
        pl[blk] = sl[0] * e0 + sl[1] * e1 + sl[2] * e2 + sl[3] * e3;
    }
    #pragma unroll
    for (int dx = tid; dx < DXX; dx += 256) {
        pacc[(size_t)blk * DXX + dx] =
            sacc[0][dx] * e0 + sacc[1][dx] * e1 + sacc[2][dx] * e2 + sacc[3][dx] * e3;
    }
}

// ---------------------------------------------------------------------------
// Kernel 3: merge the SPLITS partials per batch and normalize.
// Lane-parallel scan of the 32 partials (was a serial tid==0 loop).
// ---------------------------------------------------------------------------
__global__ __launch_bounds__(256) void attn_finalize(
        const float* __restrict__ pm, const float* __restrict__ pl,
        const float* __restrict__ pacc, float* __restrict__ out) {
    int b = blockIdx.x;
    int tid = threadIdx.x;

    __shared__ float e[SPLITS];
    __shared__ float invL;
    if (tid < 32) {
        const float mv = pm[b * SPLITS + tid];
        const float lv = pl[b * SPLITS + tid];
        float M = mv;
        #pragma unroll
        for (int off = 16; off > 0; off >>= 1) M = fmaxf(M, __shfl_xor(M, off, 64));
        const float ei = __expf(mv - M);
        e[tid] = ei;
        float L = lv * ei;
        #pragma unroll
        for (int off = 16; off > 0; off >>= 1) L += __shfl_xor(L, off, 64);
        if (tid == 0) invL = 1.f / L;
    }
    __syncthreads();

    #pragma unroll
    for (int dx = tid; dx < DXX; dx += 256) {
        float v = 0.f;
        for (int i = 0; i < SPLITS; ++i)
            v = fmaf(pacc[(size_t)(b * SPLITS + i) * DXX + dx], e[i], v);
        out[b * DXX + dx] = v * invL;
    }
}

// ---------------------------------------------------------------------------
extern "C" void kernel_launch(void* const* d_in, const int* in_sizes, int n_in,
                              void* d_out, int out_size, void* d_ws, size_t ws_size,
                              hipStream_t stream) {
    const float* x  = (const float*)d_in[0];  // [B,S,DX]
    const float* qm = (const float*)d_in[1];  // [B,Q,DQ]
    const float* W  = (const float*)d_in[2];  // [DQ,DX]
    const float* p  = (const float*)d_in[3];  // [Q,1]
    float* out = (float*)d_out;               // [B,DX]

    float* ws    = (float*)d_ws;
    float* first = ws;                        // B*DX          = 32768 floats
    float* pm    = first + BB * DXX;          // B*SPLITS      = 2048
    float* pl    = pm + BB * SPLITS;          // B*SPLITS      = 2048
    float* pacc  = pl + BB * SPLITS;          // B*SPLITS*DX   = 1048576 floats (4 MB)

    compute_first<<<BB, 512, 0, stream>>>(qm, W, p, first);
    attn_partial<<<BB * SPLITS, 256, 0, stream>>>(x, first, pm, pl, pacc);
    attn_finalize<<<BB, 256, 0, stream>>>(pm, pl, pacc, out);
}

// Round 2
// 986.528 us; speedup vs baseline: 1.0031x; 1.0031x over previous
//
#include <hip/hip_runtime.h>
#include <math.h>

#define BB 64
#define SS 4096
#define DXX 512
#define QQ 128
#define DQQ 512
#define SPLITS 32
#define CHUNK (SS / SPLITS)            // 128 rows per block
#define NWAVES 4
#define ROWS_PER_WAVE (CHUNK / NWAVES) // 32
#define RB 4                           // rows per group
#define NGROUPS (ROWS_PER_WAVE / RB)   // 8 groups per wave

typedef float v4 __attribute__((ext_vector_type(4)));

// ---------------------------------------------------------------------------
// Kernel 1: first[b,:] = (sum_q p[q]*query[b,q,:]) @ W        [B, DX]
// ---------------------------------------------------------------------------
__global__ __launch_bounds__(512) void compute_first(
        const float* __restrict__ qm, const float* __restrict__ W,
        const float* __restrict__ p, float* __restrict__ first) {
    int b = blockIdx.x;
    int t = threadIdx.x;                    // 0..511
    __shared__ float sp[QQ];
    __shared__ float snq[DQQ];
    if (t < QQ) sp[t] = p[t];
    __syncthreads();

    const float* qb = qm + (size_t)b * QQ * DQQ + t;
    float acc = 0.f;
    #pragma unroll 8
    for (int q = 0; q < QQ; ++q) acc = fmaf(qb[(size_t)q * DQQ], sp[q], acc);
    snq[t] = acc;
    __syncthreads();

    float f = 0.f;
    #pragma unroll 8
    for (int dq = 0; dq < DQQ; ++dq) f = fmaf(snq[dq], W[(size_t)dq * DXX + t], f);
    first[b * DXX + t] = f;
}

// ---------------------------------------------------------------------------
// Kernel 2: flash-style single pass over x. One wave per s-row, RB=4 rows per
// group, register double-buffered. R1 post-mortem: with __launch_bounds__(256,4)
// alone the allocator chased 8 waves/EU (VGPR=64) and spilled every prefetch
// buffer to scratch (665 MB of scratch writes, 1.35 TB/s useful BW).
// amdgpu_waves_per_eu(4,4) pins the occupancy range so the allocator gets the
// full 128-VGPR budget and the two 32-VGPR buffers stay in registers.
// Branchless online softmax (alpha == 1.0f on the common path) keeps the
// pipeline free of exec-mask divergence.
// Grid: B*SPLITS = 2048 blocks x 256 threads.
// ---------------------------------------------------------------------------
__global__ __launch_bounds__(256)
__attribute__((amdgpu_waves_per_eu(4, 4)))
void attn_partial(
        const float* __restrict__ x, const float* __restrict__ first,
        float* __restrict__ pm, float* __restrict__ pl,
        float* __restrict__ pacc) {
    const int blk  = blockIdx.x;
    const int b    = blk / SPLITS;
    const int sp   = blk % SPLITS;
    const int tid  = threadIdx.x;
    const int wave = tid >> 6;
    const int lane = tid & 63;

    const float* fb = first + b * DXX;
    const v4 f0 = *(const v4*)(fb + lane * 4);
    const v4 f1 = *(const v4*)(fb + 256 + lane * 4);

    float m = -1e30f, l = 0.f;
    v4 a0 = {0.f, 0.f, 0.f, 0.f};
    v4 a1 = {0.f, 0.f, 0.f, 0.f};

    // this wave's first row; its rows stride NWAVES within the chunk
    const float* xw = x + (size_t)b * SS * DXX
                        + (size_t)(sp * CHUNK + wave) * DXX + lane * 4;
    const size_t rstep = (size_t)NWAVES * DXX;   // floats between this wave's rows

    v4 pa0[RB], pa1[RB], pb0[RB], pb1[RB];

#define LOADG(buf0, buf1, g)                                                 \
    {                                                                        \
        _Pragma("unroll")                                                    \
        for (int r = 0; r < RB; ++r) {                                       \
            const float* xr = xw + (size_t)((g) * RB + r) * rstep;           \
            buf0[r] = *(const v4*)(xr);                                      \
            buf1[r] = *(const v4*)(xr + 256);                                \
        }                                                                    \
    }

#define PROCESS(buf0, buf1)                                                  \
    {                                                                        \
        float d[RB];                                                         \
        _Pragma("unroll")                                                    \
        for (int r = 0; r < RB; ++r) {                                       \
            v4 t4 = f0 * buf0[r] + f1 * buf1[r];                             \
            d[r] = (t4.x + t4.y) + (t4.z + t4.w);                            \
        }                                                                    \
        _Pragma("unroll")                                                    \
        for (int off = 32; off > 0; off >>= 1) {                             \
            _Pragma("unroll")                                                \
            for (int r = 0; r < RB; ++r) d[r] += __shfl_xor(d[r], off, 64);  \
        }                                                                    \
        _Pragma("unroll")                                                    \
        for (int r = 0; r < RB; ++r) {                                       \
            const float nm    = fmaxf(m, d[r]);                              \
            const float alpha = __expf(m - nm);      /* == 1.0f usually */   \
            const float w     = __expf(d[r] - nm);                           \
            m = nm;                                                          \
            l = fmaf(l, alpha, w);                                           \
            a0 = a0 * alpha + buf0[r] * w;                                   \
            a1 = a1 * alpha + buf1[r] * w;                                   \
        }                                                                    \
    }

    // prologue: preload group 0
    LOADG(pa0, pa1, 0);

    // steady state: always one full group (8 x dwordx4 / lane) in flight
    #pragma unroll
    for (int g = 0; g < NGROUPS - 2; g += 2) {
        LOADG(pb0, pb1, g + 1);
        PROCESS(pa0, pa1);
        LOADG(pa0, pa1, g + 2);
        PROCESS(pb0, pb1);
    }
    // epilogue: groups NGROUPS-2 and NGROUPS-1 (no out-of-bounds prefetch)
    LOADG(pb0, pb1, NGROUPS - 1);
    PROCESS(pa0, pa1);
    PROCESS(pb0, pb1);

#undef LOADG
#undef PROCESS

    // merge the 4 waves of this block in LDS
    __shared__ float sm[NWAVES];
    __shared__ float sl[NWAVES];
    __shared__ float sacc[NWAVES][DXX];     // 8 KiB
    if (lane == 0) { sm[wave] = m; sl[wave] = l; }
    float* sa = sacc[wave];
    *(v4*)(sa + lane * 4)       = a0;
    *(v4*)(sa + 256 + lane * 4) = a1;
    __syncthreads();

    const float M  = fmaxf(fmaxf(sm[0], sm[1]), fmaxf(sm[2], sm[3]));
    const float e0 = __expf(sm[0] - M), e1 = __expf(sm[1] - M);
    const float e2 = __expf(sm[2] - M), e3 = __expf(sm[3] - M);
    if (tid == 0) {
        pm[blk] = M;
        pl[blk] = sl[0] * e0 + sl[1] * e1 + sl[2] * e2 + sl[3] * e3;
    }
    #pragma unroll
    for (int dx = tid; dx < DXX; dx += 256) {
        pacc[(size_t)blk * DXX + dx] =
            sacc[0][dx] * e0 + sacc[1][dx] * e1 + sacc[2][dx] * e2 + sacc[3][dx] * e3;
    }
}

// ---------------------------------------------------------------------------
// Kernel 3: merge the SPLITS partials per batch and normalize.
// ---------------------------------------------------------------------------
__global__ __launch_bounds__(256) void attn_finalize(
        const float* __restrict__ pm, const float* __restrict__ pl,
        const float* __restrict__ pacc, float* __restrict__ out) {
    int b = blockIdx.x;
    int tid = threadIdx.x;

    __shared__ float e[SPLITS];
    __shared__ float invL;
    if (tid < 32) {
        const float mv = pm[b * SPLITS + tid];
        const float lv = pl[b * SPLITS + tid];
        float M = mv;
        #pragma unroll
        for (int off = 16; off > 0; off >>= 1) M = fmaxf(M, __shfl_xor(M, off, 64));
        const float ei = __expf(mv - M);
        e[tid] = ei;
        float L = lv * ei;
        #pragma unroll
        for (int off = 16; off > 0; off >>= 1) L += __shfl_xor(L, off, 64);
        if (tid == 0) invL = 1.f / L;
    }
    __syncthreads();

    #pragma unroll
    for (int dx = tid; dx < DXX; dx += 256) {
        float v = 0.f;
        for (int i = 0; i < SPLITS; ++i)
            v = fmaf(pacc[(size_t)(b * SPLITS + i) * DXX + dx], e[i], v);
        out[b * DXX + dx] = v * invL;
    }
}

// ---------------------------------------------------------------------------
extern "C" void kernel_launch(void* const* d_in, const int* in_sizes, int n_in,
                              void* d_out, int out_size, void* d_ws, size_t ws_size,
                              hipStream_t stream) {
    const float* x  = (const float*)d_in[0];  // [B,S,DX]
    const float* qm = (const float*)d_in[1];  // [B,Q,DQ]
    const float* W  = (const float*)d_in[2];  // [DQ,DX]
    const float* p  = (const float*)d_in[3];  // [Q,1]
    float* out = (float*)d_out;               // [B,DX]

    float* ws    = (float*)d_ws;
    float* first = ws;                        // B*DX          = 32768 floats
    float* pm    = first + BB * DXX;          // B*SPLITS      = 2048
    float* pl    = pm + BB * SPLITS;          // B*SPLITS      = 2048
    float* pacc  = pl + BB * SPLITS;          // B*SPLITS*DX   = 1048576 floats (4 MB)

    compute_first<<<BB, 512, 0, stream>>>(qm, W, p, first);
    attn_partial<<<BB * SPLITS, 256, 0, stream>>>(x, first, pm, pl, pacc);
    attn_finalize<<<BB, 256, 0, stream>>>(pm, pl, pacc, out);
}

// Round 3
// 732.087 us; speedup vs baseline: 1.3517x; 1.3476x over previous
//
#include <hip/hip_runtime.h>
#include <math.h>

#define BB 64
#define SS 4096
#define DXX 512
#define QQ 128
#define DQQ 512
#define SPLITS 32
#define CHUNK (SS / SPLITS)            // 128 rows per block
#define NWAVES 4
#define ROWS_PER_WAVE (CHUNK / NWAVES) // 32

typedef float v4 __attribute__((ext_vector_type(4)));

// ---------------------------------------------------------------------------
// Kernel 1: first[b,:] = (sum_q p[q]*query[b,q,:]) @ W        [B, DX]
// ---------------------------------------------------------------------------
__global__ __launch_bounds__(512) void compute_first(
        const float* __restrict__ qm, const float* __restrict__ W,
        const float* __restrict__ p, float* __restrict__ first) {
    int b = blockIdx.x;
    int t = threadIdx.x;                    // 0..511
    __shared__ float sp[QQ];
    __shared__ float snq[DQQ];
    if (t < QQ) sp[t] = p[t];
    __syncthreads();

    const float* qb = qm + (size_t)b * QQ * DQQ + t;
    float acc = 0.f;
    #pragma unroll 8
    for (int q = 0; q < QQ; ++q) acc = fmaf(qb[(size_t)q * DQQ], sp[q], acc);
    snq[t] = acc;
    __syncthreads();

    float f = 0.f;
    #pragma unroll 8
    for (int dq = 0; dq < DQQ; ++dq) f = fmaf(snq[dq], W[(size_t)dq * DXX + t], f);
    first[b * DXX + t] = f;
}

// ---------------------------------------------------------------------------
// Kernel 2: flash-style single pass over x.
// R2 post-mortem: neither __launch_bounds__(256,4) nor amdgpu_waves_per_eu(4,4)
// stopped the allocator from targeting 64 VGPRs and spilling the prefetch
// buffers (665 MB scratch writes). Structural fix instead: shrink the live set
// so it FITS in 64 VGPRs. All 8192 waves are co-resident at 8 blocks/CU, so
// per-wave BW share is ~0.77 GB/s -> a 4 KB row-pair takes ~12.8k cycles to
// deliver vs ~900 cy latency: TLP saturates HBM without any register
// double-buffer. RB=2, single-buffered, unroll pinned to 1 so the compiler
// cannot software-pipeline register pressure back up.
// Live set: f0,f1(8) + a0,a1(8) + 4 x v4 row data(16) + scalars ~= 50 VGPR.
// Grid: B*SPLITS = 2048 blocks x 256 threads.
// ---------------------------------------------------------------------------
__global__ __launch_bounds__(256) void attn_partial(
        const float* __restrict__ x, const float* __restrict__ first,
        float* __restrict__ pm, float* __restrict__ pl,
        float* __restrict__ pacc) {
    const int blk  = blockIdx.x;
    const int b    = blk / SPLITS;
    const int sp   = blk % SPLITS;
    const int tid  = threadIdx.x;
    const int wave = tid >> 6;
    const int lane = tid & 63;

    const float* fb = first + b * DXX;
    const v4 f0 = *(const v4*)(fb + lane * 4);
    const v4 f1 = *(const v4*)(fb + 256 + lane * 4);

    float m = -1e30f, l = 0.f;
    v4 a0 = {0.f, 0.f, 0.f, 0.f};
    v4 a1 = {0.f, 0.f, 0.f, 0.f};

    // this wave's first row; its rows stride NWAVES within the chunk
    const float* xw = x + (size_t)b * SS * DXX
                        + (size_t)(sp * CHUNK + wave) * DXX + lane * 4;
    const size_t rstep = (size_t)NWAVES * DXX;   // floats between this wave's rows

    #pragma unroll 1
    for (int i = 0; i < ROWS_PER_WAVE; i += 2) {
        const float* xr0 = xw + (size_t)i * rstep;
        const float* xr1 = xr0 + rstep;
        const v4 x00 = *(const v4*)(xr0);
        const v4 x01 = *(const v4*)(xr0 + 256);
        const v4 x10 = *(const v4*)(xr1);
        const v4 x11 = *(const v4*)(xr1 + 256);

        v4 t0 = f0 * x00 + f1 * x01;
        v4 t1 = f0 * x10 + f1 * x11;
        float d0 = (t0.x + t0.y) + (t0.z + t0.w);
        float d1 = (t1.x + t1.y) + (t1.z + t1.w);

        #pragma unroll
        for (int off = 32; off > 0; off >>= 1) {
            d0 += __shfl_xor(d0, off, 64);
            d1 += __shfl_xor(d1, off, 64);
        }

        // branchless online softmax; alpha == 1.0f exactly on the common path
        {
            const float nm    = fmaxf(m, d0);
            const float alpha = __expf(m - nm);
            const float w     = __expf(d0 - nm);
            m = nm;
            l = fmaf(l, alpha, w);
            a0 = a0 * alpha + x00 * w;
            a1 = a1 * alpha + x01 * w;
        }
        {
            const float nm    = fmaxf(m, d1);
            const float alpha = __expf(m - nm);
            const float w     = __expf(d1 - nm);
            m = nm;
            l = fmaf(l, alpha, w);
            a0 = a0 * alpha + x10 * w;
            a1 = a1 * alpha + x11 * w;
        }
    }

    // merge the 4 waves of this block in LDS
    __shared__ float sm[NWAVES];
    __shared__ float sl[NWAVES];
    __shared__ float sacc[NWAVES][DXX];     // 8 KiB
    if (lane == 0) { sm[wave] = m; sl[wave] = l; }
    float* sa = sacc[wave];
    *(v4*)(sa + lane * 4)       = a0;
    *(v4*)(sa + 256 + lane * 4) = a1;
    __syncthreads();

    const float M  = fmaxf(fmaxf(sm[0], sm[1]), fmaxf(sm[2], sm[3]));
    const float e0 = __expf(sm[0] - M), e1 = __expf(sm[1] - M);
    const float e2 = __expf(sm[2] - M), e3 = __expf(sm[3] - M);
    if (tid == 0) {
        pm[blk] = M;
        pl[blk] = sl[0] * e0 + sl[1] * e1 + sl[2] * e2 + sl[3] * e3;
    }
    #pragma unroll
    for (int dx = tid; dx < DXX; dx += 256) {
        pacc[(size_t)blk * DXX + dx] =
            sacc[0][dx] * e0 + sacc[1][dx] * e1 + sacc[2][dx] * e2 + sacc[3][dx] * e3;
    }
}

// ---------------------------------------------------------------------------
// Kernel 3: merge the SPLITS partials per batch and normalize.
// ---------------------------------------------------------------------------
__global__ __launch_bounds__(256) void attn_finalize(
        const float* __restrict__ pm, const float* __restrict__ pl,
        const float* __restrict__ pacc, float* __restrict__ out) {
    int b = blockIdx.x;
    int tid = threadIdx.x;

    __shared__ float e[SPLITS];
    __shared__ float invL;
    if (tid < 32) {
        const float mv = pm[b * SPLITS + tid];
        const float lv = pl[b * SPLITS + tid];
        float M = mv;
        #pragma unroll
        for (int off = 16; off > 0; off >>= 1) M = fmaxf(M, __shfl_xor(M, off, 64));
        const float ei = __expf(mv - M);
        e[tid] = ei;
        float L = lv * ei;
        #pragma unroll
        for (int off = 16; off > 0; off >>= 1) L += __shfl_xor(L, off, 64);
        if (tid == 0) invL = 1.f / L;
    }
    __syncthreads();

    #pragma unroll
    for (int dx = tid; dx < DXX; dx += 256) {
        float v = 0.f;
        for (int i = 0; i < SPLITS; ++i)
            v = fmaf(pacc[(size_t)(b * SPLITS + i) * DXX + dx], e[i], v);
        out[b * DXX + dx] = v * invL;
    }
}

// ---------------------------------------------------------------------------
extern "C" void kernel_launch(void* const* d_in, const int* in_sizes, int n_in,
                              void* d_out, int out_size, void* d_ws, size_t ws_size,
                              hipStream_t stream) {
    const float* x  = (const float*)d_in[0];  // [B,S,DX]
    const float* qm = (const float*)d_in[1];  // [B,Q,DQ]
    const float* W  = (const float*)d_in[2];  // [DQ,DX]
    const float* p  = (const float*)d_in[3];  // [Q,1]
    float* out = (float*)d_out;               // [B,DX]

    float* ws    = (float*)d_ws;
    float* first = ws;                        // B*DX          = 32768 floats
    float* pm    = first + BB * DXX;          // B*SPLITS      = 2048
    float* pl    = pm + BB * SPLITS;          // B*SPLITS      = 2048
    float* pacc  = pl + BB * SPLITS;          // B*SPLITS*DX   = 1048576 floats (4 MB)

    compute_first<<<BB, 512, 0, stream>>>(qm, W, p, first);
    attn_partial<<<BB * SPLITS, 256, 0, stream>>>(x, first, pm, pl, pacc);
    attn_finalize<<<BB, 256, 0, stream>>>(pm, pl, pacc, out);
}